// Round 9
// baseline (64.734 us; speedup 1.0000x reference)
//
#include <hip/hip_runtime.h>
#include <cmath>

#define T_SEQ 4096
#define D_MODEL 1024
#define EPS 1e-6f
#define CHUNKS 32   // chunks per head: grid 512 = 2 blocks/CU (2x80KB LDS = 160KB pool)

typedef __attribute__((ext_vector_type(8))) short bf16x8;
typedef __attribute__((ext_vector_type(4))) float f32x4;

__device__ __forceinline__ float elu1(float x) { return x > 0.f ? x + 1.f : __expf(x); }

// float -> bf16 bits, round-to-nearest-even
__device__ __forceinline__ unsigned f2bf_u(float f) {
    union { float f; unsigned u; } v; v.f = f;
    unsigned r = v.u + 0x7fffu + ((v.u >> 16) & 1u);
    return r >> 16;
}
__device__ __forceinline__ short f2bf(float f) { return (short)f2bf_u(f); }
__device__ __forceinline__ unsigned packbf(float lo, float hi) {
    return f2bf_u(lo) | (f2bf_u(hi) << 16);
}
// pack 2 f32 -> 2 bf16 (RNE), dst.lo = first arg (proven R5-R8)
__device__ __forceinline__ unsigned cvt_pk_bf16(float lo, float hi) {
    unsigned r;
    asm("v_cvt_pk_bf16_f32 %0, %1, %2" : "=v"(r) : "v"(lo), "v"(hi));
    return r;
}
// 4-octet XOR swizzle key per feature-row (R5-proven)
__device__ __forceinline__ int swz(int e) { return ((e >> 2) ^ (e >> 4)) & 3; }

// ---------------------------------------------------------------------------
// Kernel A: fused 4-head partial-context blocks.
// grid = 512 (4 b x 4 head-quads x 32 chunks) -> 2 independent blocks/CU so
// one block's waves issue loads while the other sits at its barrier.
// 1024 threads (16 waves), 80KB LDS, 4 k-steps of 32 rows. Inner machinery
// (dense 1KB staged reads, swizzled transposed LDS, quadrant MFMA + ones-col
// ksum) is R7/R8-verbatim.
// ---------------------------------------------------------------------------
__global__ __launch_bounds__(1024) void ctx_fused(const float* __restrict__ K,
                                                  const float* __restrict__ V,
                                                  float* __restrict__ partial) {
    __shared__ __align__(16) short sT[2][4][2][64 * 40];  // [buf][head][mat][e][s]

    const int bb = blockIdx.x >> 7;
    const int hq = (blockIdx.x >> 5) & 3;
    const int ch = blockIdx.x & 31;
    const int tid = threadIdx.x;
    const int wave = tid >> 6, lane = tid & 63;
    const int hh = wave >> 2, qd = wave & 3, eh = qd >> 1, dh = qd & 1;
    const int g = lane >> 4, r = lane & 15;
    const int u = wave, c6 = lane;
    const int hw = c6 >> 4;
    const int eq = c6 & 15;

    const size_t base = (size_t)bb * T_SEQ * D_MODEL;
    const int s0 = ch * 128;
    const int colb = hq * 256;

    f32x4 acc[2][2], accs[2];
#pragma unroll
    for (int i = 0; i < 2; ++i)
#pragma unroll
        for (int q = 0; q < 4; ++q) { accs[i][q] = 0.f; acc[i][0][q] = 0.f; acc[i][1][q] = 0.f; }

    bf16x8 ones;
    const short ob = (r == 0) ? (short)0x3F80 : (short)0;
#pragma unroll
    for (int j = 0; j < 8; ++j) ones[j] = ob;

    float4 kf[2], vf[2];
    auto load_tile = [&](int kt) {
        const float* Kp = K + base + (size_t)(s0 + 32 * kt + 2 * u) * D_MODEL + colb + 4 * c6;
        const float* Vp = V + base + (size_t)(s0 + 32 * kt + 2 * u) * D_MODEL + colb + 4 * c6;
        kf[0] = *(const float4*)Kp;
        kf[1] = *(const float4*)(Kp + D_MODEL);
        vf[0] = *(const float4*)Vp;
        vf[1] = *(const float4*)(Vp + D_MODEL);
    };
    auto store_tile = [&](int buf) {
        short* tk = &sT[buf][hw][0][0];
        short* tv = &sT[buf][hw][1][0];
        const float* k0 = (const float*)&kf[0];
        const float* k1 = (const float*)&kf[1];
        const float* v0 = (const float*)&vf[0];
        const float* v1 = (const float*)&vf[1];
        const int sl2 = 2 * ((u & 3) ^ (hw & 3));
#pragma unroll
        for (int i = 0; i < 4; ++i) {
            const int e = 4 * eq + i;
            const int off = e * 40 + 8 * ((u >> 2) ^ swz(e) ^ (hw & 3)) + sl2;
            *(unsigned*)&tk[off] = packbf(elu1(k0[i]), elu1(k1[i]));
            *(unsigned*)&tv[off] = packbf(v0[i], v1[i]);
        }
    };
    auto compute = [&](int buf) {
        const short* tk = &sT[buf][hh][0][0];
        const short* tv = &sT[buf][hh][1][0];
        const int h3 = hh & 3;
        bf16x8 a[2], bv[2];
#pragma unroll
        for (int mi = 0; mi < 2; ++mi) {
            const int e = 32 * eh + 16 * mi + r;
            a[mi] = *(const bf16x8*)&tk[e * 40 + 8 * (g ^ swz(e) ^ h3)];
        }
#pragma unroll
        for (int ni = 0; ni < 2; ++ni) {
            const int d = 32 * dh + 16 * ni + r;
            bv[ni] = *(const bf16x8*)&tv[d * 40 + 8 * (g ^ swz(d) ^ h3)];
        }
#pragma unroll
        for (int mi = 0; mi < 2; ++mi) {
#pragma unroll
            for (int ni = 0; ni < 2; ++ni)
                acc[mi][ni] = __builtin_amdgcn_mfma_f32_16x16x32_bf16(a[mi], bv[ni], acc[mi][ni], 0, 0, 0);
            if (dh == 0)
                accs[mi] = __builtin_amdgcn_mfma_f32_16x16x32_bf16(a[mi], ones, accs[mi], 0, 0, 0);
        }
    };

    load_tile(0);
    store_tile(0);
    __syncthreads();
#pragma unroll 1
    for (int t = 0; t < 4; ++t) {
        if (t < 3) load_tile(t + 1);
        compute(t & 1);
        if (t < 3) store_tile((t + 1) & 1);
        __syncthreads();
    }

    float* slab = partial + ((size_t)((bb * 16 + hq * 4 + hh) * CHUNKS + ch)) * 4160;
#pragma unroll
    for (int mi = 0; mi < 2; ++mi)
#pragma unroll
        for (int ni = 0; ni < 2; ++ni)
            *(f32x4*)&slab[qd * 1024 + (mi * 2 + ni) * 256 + lane * 4] = acc[mi][ni];
    if (dh == 0 && r == 0) {
#pragma unroll
        for (int mi = 0; mi < 2; ++mi)
#pragma unroll
            for (int q = 0; q < 4; ++q)
                slab[4096 + 32 * eh + 16 * mi + 4 * g + q] = accs[mi][q];
    }
}

// ---------------------------------------------------------------------------
// Kernel A2: sum 32 chunk blobs -> TRANSPOSED bf16 context, fragment-ready.
// CT[d][e] = bf16(ctx[e][d]) for d<64; CT[64][e] = bf16(ksum[e]).
// Per head 4160 shorts (8.3 KB). grid = 256 (64 heads x 4 parts).
// ---------------------------------------------------------------------------
__global__ __launch_bounds__(256) void ctx_reduce(const float* __restrict__ partial,
                                                  ushort* __restrict__ ctxbf) {
    const int head = blockIdx.x >> 2, part = blockIdx.x & 3;
    const float* pbase = partial + (size_t)head * CHUNKS * 4160;
    ushort* cbase = ctxbf + (size_t)head * 4160;
    const int lo = part * 260;
    for (int i4 = lo + threadIdx.x; i4 < lo + 260; i4 += 256) {
        f32x4 s;
#pragma unroll
        for (int k = 0; k < 4; ++k) s[k] = 0.f;
#pragma unroll
        for (int c = 0; c < CHUNKS; ++c) {
            const f32x4 v = *(const f32x4*)&pbase[(size_t)c * 4160 + i4 * 4];
#pragma unroll
            for (int k = 0; k < 4; ++k) s[k] += v[k];
        }
        const int f0 = i4 * 4;
        if (f0 < 4096) {
#pragma unroll
            for (int k = 0; k < 4; ++k) {
                const int f = f0 + k;
                const int qd = f >> 10, t2 = (f >> 8) & 3, ln = (f >> 2) & 63, q = f & 3;
                const int e = 32 * (qd >> 1) + 16 * (t2 >> 1) + 4 * (ln >> 4) + q;
                const int d = 32 * (qd & 1) + 16 * (t2 & 1) + (ln & 15);
                cbase[d * 64 + e] = (ushort)f2bf(s[k]);
            }
        } else {
#pragma unroll
            for (int k = 0; k < 4; ++k) cbase[f0 + k] = (ushort)f2bf(s[k]);  // ksum row
        }
    }
}

// ---------------------------------------------------------------------------
// Kernel B: out = (Q' ctx) / (Q' ksum + eps) via MFMA. (R8-verbatim, proven)
// grid = 64 heads * 16 row-chunks, block = 256 (4 waves x 64 rows).
// ---------------------------------------------------------------------------
__global__ __launch_bounds__(256, 4) void attn_out(const float* __restrict__ Q,
                                                   const ushort* __restrict__ ctxbf,
                                                   float* __restrict__ out) {
    const int head = blockIdx.x >> 4, nb = blockIdx.x & 15;
    const int b = head >> 4, h = head & 15;
    const int tid = threadIdx.x, wave = tid >> 6, lane = tid & 63;
    const int g = lane >> 4, r = lane & 15;
    const ushort* C = ctxbf + (size_t)head * 4160;

    bf16x8 bfr[2][5];
#pragma unroll
    for (int kt = 0; kt < 2; ++kt) {
#pragma unroll
        for (int n = 0; n < 4; ++n)
            bfr[kt][n] = *(const bf16x8*)&C[(16 * n + r) * 64 + kt * 32 + 8 * g];
        bf16x8 ks = *(const bf16x8*)&C[4096 + kt * 32 + 8 * g];
        if (r != 0) {
#pragma unroll
            for (int j = 0; j < 8; ++j) ks[j] = 0;
        }
        bfr[kt][4] = ks;
    }

    const int n0 = nb * 256 + wave * 64;
    const float* qbase = Q + ((size_t)b * T_SEQ + n0) * D_MODEL + (size_t)h * 64;

    f32x4 acc[4][5];
#pragma unroll
    for (int m = 0; m < 4; ++m)
#pragma unroll
        for (int n = 0; n < 5; ++n)
#pragma unroll
            for (int q = 0; q < 4; ++q) acc[m][n][q] = 0.f;

    union U8 { unsigned u[4]; bf16x8 v; };
#pragma unroll
    for (int kt = 0; kt < 2; ++kt)
#pragma unroll
        for (int m = 0; m < 4; ++m) {
            const float* qp = qbase + (size_t)(16 * m + r) * D_MODEL + kt * 32 + 8 * g;
            const float4 q1 = *(const float4*)qp;
            const float4 q2 = *(const float4*)(qp + 4);
            U8 a;
            a.u[0] = cvt_pk_bf16(elu1(q1.x), elu1(q1.y));
            a.u[1] = cvt_pk_bf16(elu1(q1.z), elu1(q1.w));
            a.u[2] = cvt_pk_bf16(elu1(q2.x), elu1(q2.y));
            a.u[3] = cvt_pk_bf16(elu1(q2.z), elu1(q2.w));
#pragma unroll
            for (int n = 0; n < 5; ++n)
                acc[m][n] = __builtin_amdgcn_mfma_f32_16x16x32_bf16(a.v, bfr[kt][n], acc[m][n], 0, 0, 0);
        }

#pragma unroll
    for (int m = 0; m < 4; ++m) {
        float dinv[4];
#pragma unroll
        for (int q = 0; q < 4; ++q)
            dinv[q] = 1.f / (__shfl(acc[m][4][q], lane & 48) + EPS);
#pragma unroll
        for (int q = 0; q < 4; ++q) {
            float* op = out + ((size_t)b * T_SEQ + n0 + 16 * m + 4 * g + q) * D_MODEL
                        + (size_t)h * 64 + r;
#pragma unroll
            for (int n = 0; n < 4; ++n) op[16 * n] = acc[m][n][q] * dinv[q];
        }
    }
}

extern "C" void kernel_launch(void* const* d_in, const int* in_sizes, int n_in,
                              void* d_out, int out_size, void* d_ws, size_t ws_size,
                              hipStream_t stream) {
    const float* Q = (const float*)d_in[0];
    const float* K = (const float*)d_in[1];
    const float* V = (const float*)d_in[2];
    float* out = (float*)d_out;

    // Partials (64*32*4160 floats = 34 MB) live in d_out-as-scratch (67 MB);
    // consumed by ctx_reduce, then d_out is fully overwritten by attn_out.
    float* partial  = out;
    ushort* ctxbf   = (ushort*)d_ws;                   // 64*4160 shorts (~0.5 MB)

    hipLaunchKernelGGL(ctx_fused,  dim3(512),  dim3(1024), 0, stream, K, V, partial);
    hipLaunchKernelGGL(ctx_reduce, dim3(256),  dim3(256),  0, stream, partial, ctxbf);
    hipLaunchKernelGGL(attn_out,   dim3(1024), dim3(256),  0, stream, Q, ctxbf, out);
}

// Round 10
// 58.026 us; speedup vs baseline: 1.1156x; 1.1156x over previous
//
#include <hip/hip_runtime.h>
#include <cmath>

#define T_SEQ 4096
#define D_MODEL 1024
#define EPS 1e-6f
#define CHUNKS 16   // grid 256 = 1 block/CU; depth-3 reg pipeline hides latency in-block

typedef __attribute__((ext_vector_type(8))) short bf16x8;
typedef __attribute__((ext_vector_type(4))) float f32x4;

__device__ __forceinline__ float elu1(float x) { return x > 0.f ? x + 1.f : __expf(x); }

// float -> bf16 bits, round-to-nearest-even
__device__ __forceinline__ unsigned f2bf_u(float f) {
    union { float f; unsigned u; } v; v.f = f;
    unsigned r = v.u + 0x7fffu + ((v.u >> 16) & 1u);
    return r >> 16;
}
__device__ __forceinline__ short f2bf(float f) { return (short)f2bf_u(f); }
__device__ __forceinline__ unsigned packbf(float lo, float hi) {
    return f2bf_u(lo) | (f2bf_u(hi) << 16);
}
// pack 2 f32 -> 2 bf16 (RNE), dst.lo = first arg (proven R5-R8)
__device__ __forceinline__ unsigned cvt_pk_bf16(float lo, float hi) {
    unsigned r;
    asm("v_cvt_pk_bf16_f32 %0, %1, %2" : "=v"(r) : "v"(lo), "v"(hi));
    return r;
}
// 4-octet XOR swizzle key per feature-row (R5-proven)
__device__ __forceinline__ int swz(int e) { return ((e >> 2) ^ (e >> 4)) & 3; }

// ---------------------------------------------------------------------------
// Kernel A: fused 4-head partial-context blocks, depth-3 load pipeline.
// grid = 256 (4 b x 4 head-quads x 16 chunks), 1024 threads (16 waves), 80KB.
// Inner machinery (dense 1KB staged reads, swizzled transposed LDS, quadrant
// MFMA + ones-col ksum) is R7/R8-verbatim. New: 4 register slots; loads for
// tile t+3 are issued at step t, so the store of tile t+1 waits on a COUNTED
// vmcnt (2 tiles remain in flight) instead of vmcnt(0); the step barrier is
// raw s_barrier + lgkmcnt(0) only (no vmcnt drain). Only LDS crosses the
// barrier (write -> lgkmcnt(0) -> barrier -> read; double-buffered).
// ---------------------------------------------------------------------------
__global__ __launch_bounds__(1024) void ctx_fused(const float* __restrict__ K,
                                                  const float* __restrict__ V,
                                                  float* __restrict__ partial) {
    __shared__ __align__(16) short sT[2][4][2][64 * 40];  // [buf][head][mat][e][s]

    const int bb = blockIdx.x >> 6;
    const int hq = (blockIdx.x >> 4) & 3;
    const int ch = blockIdx.x & 15;
    const int tid = threadIdx.x;
    const int wave = tid >> 6, lane = tid & 63;
    const int hh = wave >> 2, qd = wave & 3, eh = qd >> 1, dh = qd & 1;
    const int g = lane >> 4, r = lane & 15;
    const int u = wave, c6 = lane;
    const int hw = c6 >> 4;
    const int eq = c6 & 15;

    const size_t base = (size_t)bb * T_SEQ * D_MODEL;
    const int s0 = ch * 256;
    const int colb = hq * 256;

    f32x4 acc[2][2], accs[2];
#pragma unroll
    for (int i = 0; i < 2; ++i)
#pragma unroll
        for (int q = 0; q < 4; ++q) { accs[i][q] = 0.f; acc[i][0][q] = 0.f; acc[i][1][q] = 0.f; }

    bf16x8 ones;
    const short ob = (r == 0) ? (short)0x3F80 : (short)0;
#pragma unroll
    for (int j = 0; j < 8; ++j) ones[j] = ob;

    // 4 register slots (static indexing via full unroll)
    float4 kf[4][2], vf[4][2];
    auto load_tile = [&](int kt, int slot) {
        const float* Kp = K + base + (size_t)(s0 + 32 * kt + 2 * u) * D_MODEL + colb + 4 * c6;
        const float* Vp = V + base + (size_t)(s0 + 32 * kt + 2 * u) * D_MODEL + colb + 4 * c6;
        kf[slot][0] = *(const float4*)Kp;
        kf[slot][1] = *(const float4*)(Kp + D_MODEL);
        vf[slot][0] = *(const float4*)Vp;
        vf[slot][1] = *(const float4*)(Vp + D_MODEL);
    };
    auto store_tile = [&](int buf, int slot) {
        short* tk = &sT[buf][hw][0][0];
        short* tv = &sT[buf][hw][1][0];
        const float* k0 = (const float*)&kf[slot][0];
        const float* k1 = (const float*)&kf[slot][1];
        const float* v0 = (const float*)&vf[slot][0];
        const float* v1 = (const float*)&vf[slot][1];
        const int sl2 = 2 * ((u & 3) ^ (hw & 3));
#pragma unroll
        for (int i = 0; i < 4; ++i) {
            const int e = 4 * eq + i;
            const int off = e * 40 + 8 * ((u >> 2) ^ swz(e) ^ (hw & 3)) + sl2;
            *(unsigned*)&tk[off] = packbf(elu1(k0[i]), elu1(k1[i]));
            *(unsigned*)&tv[off] = packbf(v0[i], v1[i]);
        }
    };
    auto compute = [&](int buf) {
        const short* tk = &sT[buf][hh][0][0];
        const short* tv = &sT[buf][hh][1][0];
        const int h3 = hh & 3;
        bf16x8 a[2], bv[2];
#pragma unroll
        for (int mi = 0; mi < 2; ++mi) {
            const int e = 32 * eh + 16 * mi + r;
            a[mi] = *(const bf16x8*)&tk[e * 40 + 8 * (g ^ swz(e) ^ h3)];
        }
#pragma unroll
        for (int ni = 0; ni < 2; ++ni) {
            const int d = 32 * dh + 16 * ni + r;
            bv[ni] = *(const bf16x8*)&tv[d * 40 + 8 * (g ^ swz(d) ^ h3)];
        }
#pragma unroll
        for (int mi = 0; mi < 2; ++mi) {
#pragma unroll
            for (int ni = 0; ni < 2; ++ni)
                acc[mi][ni] = __builtin_amdgcn_mfma_f32_16x16x32_bf16(a[mi], bv[ni], acc[mi][ni], 0, 0, 0);
            if (dh == 0)
                accs[mi] = __builtin_amdgcn_mfma_f32_16x16x32_bf16(a[mi], ones, accs[mi], 0, 0, 0);
        }
    };

    // prologue: tiles 0,1,2 in flight; stage tile 0 (counted vmcnt for slot 0)
    load_tile(0, 0);
    load_tile(1, 1);
    load_tile(2, 2);
    store_tile(0, 0);
    asm volatile("s_waitcnt lgkmcnt(0)" ::: "memory");
    __builtin_amdgcn_s_barrier();
    __builtin_amdgcn_sched_barrier(0);

#pragma unroll
    for (int t = 0; t < 8; ++t) {
        if (t + 3 < 8) load_tile(t + 3, (t + 3) & 3);   // keep 2-3 tiles in flight
        compute(t & 1);
        if (t + 1 < 8) store_tile((t + 1) & 1, (t + 1) & 3);  // waits counted vmcnt
        __builtin_amdgcn_sched_barrier(0);
        asm volatile("s_waitcnt lgkmcnt(0)" ::: "memory");
        __builtin_amdgcn_s_barrier();
        __builtin_amdgcn_sched_barrier(0);
    }

    float* slab = partial + ((size_t)((bb * 16 + hq * 4 + hh) * CHUNKS + ch)) * 4160;
#pragma unroll
    for (int mi = 0; mi < 2; ++mi)
#pragma unroll
        for (int ni = 0; ni < 2; ++ni)
            *(f32x4*)&slab[qd * 1024 + (mi * 2 + ni) * 256 + lane * 4] = acc[mi][ni];
    if (dh == 0 && r == 0) {
#pragma unroll
        for (int mi = 0; mi < 2; ++mi)
#pragma unroll
            for (int q = 0; q < 4; ++q)
                slab[4096 + 32 * eh + 16 * mi + 4 * g + q] = accs[mi][q];
    }
}

// ---------------------------------------------------------------------------
// Kernel A2: sum 16 chunk blobs -> TRANSPOSED bf16 context, fragment-ready.
// CT[d][e] = bf16(ctx[e][d]) for d<64; CT[64][e] = bf16(ksum[e]).
// Per head 4160 shorts (8.3 KB). grid = 256 (64 heads x 4 parts).
// ---------------------------------------------------------------------------
__global__ __launch_bounds__(256) void ctx_reduce(const float* __restrict__ partial,
                                                  ushort* __restrict__ ctxbf) {
    const int head = blockIdx.x >> 2, part = blockIdx.x & 3;
    const float* pbase = partial + (size_t)head * CHUNKS * 4160;
    ushort* cbase = ctxbf + (size_t)head * 4160;
    const int lo = part * 260;
    for (int i4 = lo + threadIdx.x; i4 < lo + 260; i4 += 256) {
        f32x4 s;
#pragma unroll
        for (int k = 0; k < 4; ++k) s[k] = 0.f;
#pragma unroll
        for (int c = 0; c < CHUNKS; ++c) {
            const f32x4 v = *(const f32x4*)&pbase[(size_t)c * 4160 + i4 * 4];
#pragma unroll
            for (int k = 0; k < 4; ++k) s[k] += v[k];
        }
        const int f0 = i4 * 4;
        if (f0 < 4096) {
#pragma unroll
            for (int k = 0; k < 4; ++k) {
                const int f = f0 + k;
                const int qd = f >> 10, t2 = (f >> 8) & 3, ln = (f >> 2) & 63, q = f & 3;
                const int e = 32 * (qd >> 1) + 16 * (t2 >> 1) + 4 * (ln >> 4) + q;
                const int d = 32 * (qd & 1) + 16 * (t2 & 1) + (ln & 15);
                cbase[d * 64 + e] = (ushort)f2bf(s[k]);
            }
        } else {
#pragma unroll
            for (int k = 0; k < 4; ++k) cbase[f0 + k] = (ushort)f2bf(s[k]);  // ksum row
        }
    }
}

// ---------------------------------------------------------------------------
// Kernel B: out = (Q' ctx) / (Q' ksum + eps) via MFMA. (R8-verbatim, proven)
// grid = 64 heads * 16 row-chunks, block = 256 (4 waves x 64 rows).
// ---------------------------------------------------------------------------
__global__ __launch_bounds__(256, 4) void attn_out(const float* __restrict__ Q,
                                                   const ushort* __restrict__ ctxbf,
                                                   float* __restrict__ out) {
    const int head = blockIdx.x >> 4, nb = blockIdx.x & 15;
    const int b = head >> 4, h = head & 15;
    const int tid = threadIdx.x, wave = tid >> 6, lane = tid & 63;
    const int g = lane >> 4, r = lane & 15;
    const ushort* C = ctxbf + (size_t)head * 4160;

    bf16x8 bfr[2][5];
#pragma unroll
    for (int kt = 0; kt < 2; ++kt) {
#pragma unroll
        for (int n = 0; n < 4; ++n)
            bfr[kt][n] = *(const bf16x8*)&C[(16 * n + r) * 64 + kt * 32 + 8 * g];
        bf16x8 ks = *(const bf16x8*)&C[4096 + kt * 32 + 8 * g];
        if (r != 0) {
#pragma unroll
            for (int j = 0; j < 8; ++j) ks[j] = 0;
        }
        bfr[kt][4] = ks;
    }

    const int n0 = nb * 256 + wave * 64;
    const float* qbase = Q + ((size_t)b * T_SEQ + n0) * D_MODEL + (size_t)h * 64;

    f32x4 acc[4][5];
#pragma unroll
    for (int m = 0; m < 4; ++m)
#pragma unroll
        for (int n = 0; n < 5; ++n)
#pragma unroll
            for (int q = 0; q < 4; ++q) acc[m][n][q] = 0.f;

    union U8 { unsigned u[4]; bf16x8 v; };
#pragma unroll
    for (int kt = 0; kt < 2; ++kt)
#pragma unroll
        for (int m = 0; m < 4; ++m) {
            const float* qp = qbase + (size_t)(16 * m + r) * D_MODEL + kt * 32 + 8 * g;
            const float4 q1 = *(const float4*)qp;
            const float4 q2 = *(const float4*)(qp + 4);
            U8 a;
            a.u[0] = cvt_pk_bf16(elu1(q1.x), elu1(q1.y));
            a.u[1] = cvt_pk_bf16(elu1(q1.z), elu1(q1.w));
            a.u[2] = cvt_pk_bf16(elu1(q2.x), elu1(q2.y));
            a.u[3] = cvt_pk_bf16(elu1(q2.z), elu1(q2.w));
#pragma unroll
            for (int n = 0; n < 5; ++n)
                acc[m][n] = __builtin_amdgcn_mfma_f32_16x16x32_bf16(a.v, bfr[kt][n], acc[m][n], 0, 0, 0);
        }

#pragma unroll
    for (int m = 0; m < 4; ++m) {
        float dinv[4];
#pragma unroll
        for (int q = 0; q < 4; ++q)
            dinv[q] = 1.f / (__shfl(acc[m][4][q], lane & 48) + EPS);
#pragma unroll
        for (int q = 0; q < 4; ++q) {
            float* op = out + ((size_t)b * T_SEQ + n0 + 16 * m + 4 * g + q) * D_MODEL
                        + (size_t)h * 64 + r;
#pragma unroll
            for (int n = 0; n < 4; ++n) op[16 * n] = acc[m][n][q] * dinv[q];
        }
    }
}

extern "C" void kernel_launch(void* const* d_in, const int* in_sizes, int n_in,
                              void* d_out, int out_size, void* d_ws, size_t ws_size,
                              hipStream_t stream) {
    const float* Q = (const float*)d_in[0];
    const float* K = (const float*)d_in[1];
    const float* V = (const float*)d_in[2];
    float* out = (float*)d_out;

    // Partials (64*16*4160 floats = 17 MB) live in d_out-as-scratch; consumed
    // by ctx_reduce, then d_out is fully overwritten by attn_out.
    float* partial  = out;
    ushort* ctxbf   = (ushort*)d_ws;                   // 64*4160 shorts (~0.5 MB)

    hipLaunchKernelGGL(ctx_fused,  dim3(256),  dim3(1024), 0, stream, K, V, partial);
    hipLaunchKernelGGL(ctx_reduce, dim3(256),  dim3(256),  0, stream, partial, ctxbf);
    hipLaunchKernelGGL(attn_out,   dim3(1024), dim3(256),  0, stream, Q, ctxbf, out);
}

// Round 11
// 57.902 us; speedup vs baseline: 1.1180x; 1.0022x over previous
//
#include <hip/hip_runtime.h>
#include <cmath>

#define T_SEQ 4096
#define D_MODEL 1024
#define EPS 1e-6f
#define CHUNKS 16   // grid 256 = 1 block/CU
#define RSTRIDE 257 // f32 row stride in LDS: 1-dword pad -> column gathers 2-way/bank (free)

typedef __attribute__((ext_vector_type(8))) short bf16x8;
typedef __attribute__((ext_vector_type(4))) float f32x4;

__device__ __forceinline__ float elu1(float x) { return x > 0.f ? x + 1.f : __expf(x); }

// float -> bf16 bits, round-to-nearest-even
__device__ __forceinline__ unsigned f2bf_u(float f) {
    union { float f; unsigned u; } v; v.f = f;
    unsigned r = v.u + 0x7fffu + ((v.u >> 16) & 1u);
    return r >> 16;
}
__device__ __forceinline__ short f2bf(float f) { return (short)f2bf_u(f); }
// pack 2 f32 -> 2 bf16 (RNE), dst.lo = first arg (proven R5-R10)
__device__ __forceinline__ unsigned cvt_pk_bf16(float lo, float hi) {
    unsigned r;
    asm("v_cvt_pk_bf16_f32 %0, %1, %2" : "=v"(r) : "v"(lo), "v"(hi));
    return r;
}

// ---------------------------------------------------------------------------
// Kernel A: fused 4-head partial-context blocks, global_load_lds staging.
// grid = 256 (4 b x 4 head-quads x 16 chunks), 1024 threads (16 waves).
// Staging: one global_load_lds dwordx4 wave-instruction = one full 1-KB row
// (256 f32 covering 4 heads) -> LDS row-major f32 [32][257] per matrix,
// double-buffered (131.6 KB). Zero staging VGPRs; loads for tile t+1 are
// issued before compute(t), drained by the end-of-step barrier (m97 scheme).
// Fragments: 8x ds_read_b32 column gathers (stride 257 => 2 lanes/bank,
// free) + elu/cvt_pk in the consumer. Canonical k-mapping (k = 8g+j) for
// both A and B. Wave (hh,eh,dh) owns head hh's ctx quadrant; ones-column
// B tile gives ksum on dh==0 waves. Accumulator/slab layout = R8-verbatim.
// ---------------------------------------------------------------------------
__global__ __launch_bounds__(1024) void ctx_fused(const float* __restrict__ K,
                                                  const float* __restrict__ V,
                                                  float* __restrict__ partial) {
    __shared__ __align__(16) float sL[2][2][32 * RSTRIDE];  // [buf][K=0,V=1][row*257+col]

    const int bb = blockIdx.x >> 6;
    const int hq = (blockIdx.x >> 4) & 3;
    const int ch = blockIdx.x & 15;
    const int tid = threadIdx.x;
    const int wave = tid >> 6, lane = tid & 63;
    const int hh = wave >> 2, qd = wave & 3, eh = qd >> 1, dh = qd & 1;
    const int g = lane >> 4, r = lane & 15;
    const int u = wave;                 // staging: wave u owns rows 2u, 2u+1

    const size_t base = (size_t)bb * T_SEQ * D_MODEL;
    const int s0 = ch * 256;
    const int colb = hq * 256;

    f32x4 acc[2][2], accs[2];
#pragma unroll
    for (int i = 0; i < 2; ++i)
#pragma unroll
        for (int q = 0; q < 4; ++q) { accs[i][q] = 0.f; acc[i][0][q] = 0.f; acc[i][1][q] = 0.f; }

    bf16x8 ones;
    const short ob = (r == 0) ? (short)0x3F80 : (short)0;
#pragma unroll
    for (int j = 0; j < 8; ++j) ones[j] = ob;

    union U8 { unsigned u[4]; bf16x8 v; };

    // issue 4 direct-to-LDS row loads for tile t into buffer buf
    auto stage = [&](int t, int buf) {
        const size_t gr = base + (size_t)(s0 + 32 * t + 2 * u) * D_MODEL + colb + 4 * lane;
        const float* Kp = K + gr;
        const float* Vp = V + gr;
        float* dK = &sL[buf][0][(2 * u) * RSTRIDE];
        float* dV = &sL[buf][1][(2 * u) * RSTRIDE];
        __builtin_amdgcn_global_load_lds((const unsigned*)Kp, (unsigned*)dK, 16, 0, 0);
        __builtin_amdgcn_global_load_lds((const unsigned*)(Kp + D_MODEL),
                                         (unsigned*)(dK + RSTRIDE), 16, 0, 0);
        __builtin_amdgcn_global_load_lds((const unsigned*)Vp, (unsigned*)dV, 16, 0, 0);
        __builtin_amdgcn_global_load_lds((const unsigned*)(Vp + D_MODEL),
                                         (unsigned*)(dV + RSTRIDE), 16, 0, 0);
    };

    auto compute = [&](int buf) {
        const float* tk = &sL[buf][0][0];
        const float* tv = &sL[buf][1][0];
        const int hb = hh * 64;
        bf16x8 a[2], bv[2];
#pragma unroll
        for (int mi = 0; mi < 2; ++mi) {
            const int col = hb + 32 * eh + 16 * mi + r;
            float f[8];
#pragma unroll
            for (int j = 0; j < 8; ++j) f[j] = tk[(8 * g + j) * RSTRIDE + col];
            U8 t;
            t.u[0] = cvt_pk_bf16(elu1(f[0]), elu1(f[1]));
            t.u[1] = cvt_pk_bf16(elu1(f[2]), elu1(f[3]));
            t.u[2] = cvt_pk_bf16(elu1(f[4]), elu1(f[5]));
            t.u[3] = cvt_pk_bf16(elu1(f[6]), elu1(f[7]));
            a[mi] = t.v;
        }
#pragma unroll
        for (int ni = 0; ni < 2; ++ni) {
            const int col = hb + 32 * dh + 16 * ni + r;
            float f[8];
#pragma unroll
            for (int j = 0; j < 8; ++j) f[j] = tv[(8 * g + j) * RSTRIDE + col];
            U8 t;
            t.u[0] = cvt_pk_bf16(f[0], f[1]);
            t.u[1] = cvt_pk_bf16(f[2], f[3]);
            t.u[2] = cvt_pk_bf16(f[4], f[5]);
            t.u[3] = cvt_pk_bf16(f[6], f[7]);
            bv[ni] = t.v;
        }
#pragma unroll
        for (int mi = 0; mi < 2; ++mi) {
#pragma unroll
            for (int ni = 0; ni < 2; ++ni)
                acc[mi][ni] = __builtin_amdgcn_mfma_f32_16x16x32_bf16(a[mi], bv[ni], acc[mi][ni], 0, 0, 0);
            if (dh == 0)
                accs[mi] = __builtin_amdgcn_mfma_f32_16x16x32_bf16(a[mi], ones, accs[mi], 0, 0, 0);
        }
    };

    stage(0, 0);
    __syncthreads();            // drains this wave's stage loads -> tile 0 visible
#pragma unroll 1
    for (int t = 0; t < 8; ++t) {
        if (t < 7) stage(t + 1, (t + 1) & 1);   // issue next tile (other buffer)
        compute(t & 1);
        __syncthreads();        // drain own stage loads + publish LDS
    }

    float* slab = partial + ((size_t)((bb * 16 + hq * 4 + hh) * CHUNKS + ch)) * 4160;
#pragma unroll
    for (int mi = 0; mi < 2; ++mi)
#pragma unroll
        for (int ni = 0; ni < 2; ++ni)
            *(f32x4*)&slab[qd * 1024 + (mi * 2 + ni) * 256 + lane * 4] = acc[mi][ni];
    if (dh == 0 && r == 0) {
#pragma unroll
        for (int mi = 0; mi < 2; ++mi)
#pragma unroll
            for (int q = 0; q < 4; ++q)
                slab[4096 + 32 * eh + 16 * mi + 4 * g + q] = accs[mi][q];
    }
}

// ---------------------------------------------------------------------------
// Kernel A2: sum 16 chunk blobs -> TRANSPOSED bf16 context, fragment-ready.
// CT[d][e] = bf16(ctx[e][d]) for d<64; CT[64][e] = bf16(ksum[e]).
// Per head 4160 shorts (8.3 KB). grid = 256 (64 heads x 4 parts).
// ---------------------------------------------------------------------------
__global__ __launch_bounds__(256) void ctx_reduce(const float* __restrict__ partial,
                                                  ushort* __restrict__ ctxbf) {
    const int head = blockIdx.x >> 2, part = blockIdx.x & 3;
    const float* pbase = partial + (size_t)head * CHUNKS * 4160;
    ushort* cbase = ctxbf + (size_t)head * 4160;
    const int lo = part * 260;
    for (int i4 = lo + threadIdx.x; i4 < lo + 260; i4 += 256) {
        f32x4 s;
#pragma unroll
        for (int k = 0; k < 4; ++k) s[k] = 0.f;
#pragma unroll
        for (int c = 0; c < CHUNKS; ++c) {
            const f32x4 v = *(const f32x4*)&pbase[(size_t)c * 4160 + i4 * 4];
#pragma unroll
            for (int k = 0; k < 4; ++k) s[k] += v[k];
        }
        const int f0 = i4 * 4;
        if (f0 < 4096) {
#pragma unroll
            for (int k = 0; k < 4; ++k) {
                const int f = f0 + k;
                const int qd = f >> 10, t2 = (f >> 8) & 3, ln = (f >> 2) & 63, q = f & 3;
                const int e = 32 * (qd >> 1) + 16 * (t2 >> 1) + 4 * (ln >> 4) + q;
                const int d = 32 * (qd & 1) + 16 * (t2 & 1) + (ln & 15);
                cbase[d * 64 + e] = (ushort)f2bf(s[k]);
            }
        } else {
#pragma unroll
            for (int k = 0; k < 4; ++k) cbase[f0 + k] = (ushort)f2bf(s[k]);  // ksum row
        }
    }
}

// ---------------------------------------------------------------------------
// Kernel B: out = (Q' ctx) / (Q' ksum + eps) via MFMA. (R8-verbatim, proven)
// grid = 64 heads * 16 row-chunks, block = 256 (4 waves x 64 rows).
// ---------------------------------------------------------------------------
__global__ __launch_bounds__(256, 4) void attn_out(const float* __restrict__ Q,
                                                   const ushort* __restrict__ ctxbf,
                                                   float* __restrict__ out) {
    const int head = blockIdx.x >> 4, nb = blockIdx.x & 15;
    const int b = head >> 4, h = head & 15;
    const int tid = threadIdx.x, wave = tid >> 6, lane = tid & 63;
    const int g = lane >> 4, r = lane & 15;
    const ushort* C = ctxbf + (size_t)head * 4160;

    bf16x8 bfr[2][5];
#pragma unroll
    for (int kt = 0; kt < 2; ++kt) {
#pragma unroll
        for (int n = 0; n < 4; ++n)
            bfr[kt][n] = *(const bf16x8*)&C[(16 * n + r) * 64 + kt * 32 + 8 * g];
        bf16x8 ks = *(const bf16x8*)&C[4096 + kt * 32 + 8 * g];
        if (r != 0) {
#pragma unroll
            for (int j = 0; j < 8; ++j) ks[j] = 0;
        }
        bfr[kt][4] = ks;
    }

    const int n0 = nb * 256 + wave * 64;
    const float* qbase = Q + ((size_t)b * T_SEQ + n0) * D_MODEL + (size_t)h * 64;

    f32x4 acc[4][5];
#pragma unroll
    for (int m = 0; m < 4; ++m)
#pragma unroll
        for (int n = 0; n < 5; ++n)
#pragma unroll
            for (int q = 0; q < 4; ++q) acc[m][n][q] = 0.f;

    union U8 { unsigned u[4]; bf16x8 v; };
#pragma unroll
    for (int kt = 0; kt < 2; ++kt)
#pragma unroll
        for (int m = 0; m < 4; ++m) {
            const float* qp = qbase + (size_t)(16 * m + r) * D_MODEL + kt * 32 + 8 * g;
            const float4 q1 = *(const float4*)qp;
            const float4 q2 = *(const float4*)(qp + 4);
            U8 a;
            a.u[0] = cvt_pk_bf16(elu1(q1.x), elu1(q1.y));
            a.u[1] = cvt_pk_bf16(elu1(q1.z), elu1(q1.w));
            a.u[2] = cvt_pk_bf16(elu1(q2.x), elu1(q2.y));
            a.u[3] = cvt_pk_bf16(elu1(q2.z), elu1(q2.w));
#pragma unroll
            for (int n = 0; n < 5; ++n)
                acc[m][n] = __builtin_amdgcn_mfma_f32_16x16x32_bf16(a.v, bfr[kt][n], acc[m][n], 0, 0, 0);
        }

#pragma unroll
    for (int m = 0; m < 4; ++m) {
        float dinv[4];
#pragma unroll
        for (int q = 0; q < 4; ++q)
            dinv[q] = 1.f / (__shfl(acc[m][4][q], lane & 48) + EPS);
#pragma unroll
        for (int q = 0; q < 4; ++q) {
            float* op = out + ((size_t)b * T_SEQ + n0 + 16 * m + 4 * g + q) * D_MODEL
                        + (size_t)h * 64 + r;
#pragma unroll
            for (int n = 0; n < 4; ++n) op[16 * n] = acc[m][n][q] * dinv[q];
        }
    }
}

extern "C" void kernel_launch(void* const* d_in, const int* in_sizes, int n_in,
                              void* d_out, int out_size, void* d_ws, size_t ws_size,
                              hipStream_t stream) {
    const float* Q = (const float*)d_in[0];
    const float* K = (const float*)d_in[1];
    const float* V = (const float*)d_in[2];
    float* out = (float*)d_out;

    // Partials (64*16*4160 floats = 17 MB) live in d_out-as-scratch; consumed
    // by ctx_reduce, then d_out is fully overwritten by attn_out.
    float* partial  = out;
    ushort* ctxbf   = (ushort*)d_ws;                   // 64*4160 shorts (~0.5 MB)

    hipLaunchKernelGGL(ctx_fused,  dim3(256),  dim3(1024), 0, stream, K, V, partial);
    hipLaunchKernelGGL(ctx_reduce, dim3(256),  dim3(256),  0, stream, partial, ctxbf);
    hipLaunchKernelGGL(attn_out,   dim3(1024), dim3(256),  0, stream, Q, ctxbf, out);
}